// Round 9
// baseline (740.570 us; speedup 1.0000x reference)
//
#include <hip/hip_runtime.h>
#include <hip/hip_fp8.h>
#include <cstdint>
#include <cstddef>

typedef __attribute__((ext_vector_type(4))) float f32x4;
typedef __attribute__((ext_vector_type(8))) int i32x8;

#define DEVINL __device__ __forceinline__

DEVINL unsigned short f2bf(float f){
  union { float f; unsigned u; } v; v.f = f;
  unsigned r = v.u + 0x7fffu + ((v.u >> 16) & 1u);  // RNE
  return (unsigned short)(r >> 16);
}
DEVINL float bf2f(unsigned short h){
  union { unsigned u; float f; } v; v.u = ((unsigned)h) << 16;
  return v.f;
}
DEVINL unsigned char f2fp8(float f){
  __hip_fp8_e4m3 t(f);           // OCP e4m3fn, saturating
  return (unsigned char)t.__x;
}
DEVINL void gload_lds16(const void* g, void* l){
  __builtin_amdgcn_global_load_lds((const __attribute__((address_space(1))) void*)g,
                                   (__attribute__((address_space(3))) void*)l, 16, 0, 0);
}

// scale constants: activations stored x2^6, weights x2^4; descale via e8m0 MFMA scales
#define ACT_SCALE 64.0f
#define W_SCALE   16.0f
#define E8M0_ACT  121   // 2^-6
#define E8M0_W    123   // 2^-4

// ---- weight prep: Wt[n][k] = fp8(W[k][n] * 16) ----
__global__ __launch_bounds__(256) void transpose_fp8(
    const float* __restrict__ W, unsigned char* __restrict__ Wt, int K, int N)
{
  __shared__ unsigned char tile[32][33];
  int k0 = blockIdx.x * 32, n0 = blockIdx.y * 32;
  int tx = threadIdx.x & 31, ty = threadIdx.x >> 5;
  #pragma unroll
  for (int i = 0; i < 4; ++i) {
    int k = k0 + ty + 8*i, n = n0 + tx;
    tile[ty + 8*i][tx] = f2fp8(W[(size_t)k*N + n] * W_SCALE);
  }
  __syncthreads();
  #pragma unroll
  for (int i = 0; i < 4; ++i) {
    int n = n0 + ty + 8*i, k = k0 + tx;
    Wt[(size_t)n*K + k] = tile[tx][ty + 8*i];
  }
}

// ---- L1 prep: compact knn mask column j -> 21 packed (idx<<16 | bf16(W1)) ----
__global__ __launch_bounds__(256) void build_sparse(
    const float* __restrict__ C1, const float* __restrict__ W1,
    unsigned* __restrict__ packed)
{
  const int j = blockIdx.x;            // 0..195
  const int w = threadIdx.x >> 6, l = threadIdx.x & 63;
  __shared__ int wcnt[4], wbase[4];
  int cnt = 0;
  #pragma unroll 4
  for (int it = 0; it < 16; ++it) {
    int k = w*1024 + it*64 + l;
    float c = C1[(size_t)k*196 + j];
    unsigned long long m = __ballot(c != 0.f);
    cnt += (int)__popcll(m);
  }
  if (l == 0) wcnt[w] = cnt;
  __syncthreads();
  if (threadIdx.x < 21) packed[j*21 + threadIdx.x] = 0;  // safety vs poison
  if (threadIdx.x == 0) {
    int b = 0;
    #pragma unroll
    for (int i = 0; i < 4; ++i) { wbase[i] = b; b += wcnt[i]; }
  }
  __syncthreads();
  int base = wbase[w];
  #pragma unroll 4
  for (int it = 0; it < 16; ++it) {
    int k = w*1024 + it*64 + l;
    float c = C1[(size_t)k*196 + j];
    unsigned long long m = __ballot(c != 0.f);
    if (c != 0.f) {
      int pos = base + (int)__popcll(m & ((1ull << l) - 1ull));
      if (pos < 21)
        packed[j*21 + pos] = ((unsigned)k << 16)
                           | (unsigned)f2bf(W1[(size_t)k*196 + j] * c);
    }
    base += (int)__popcll(m);
  }
}

// ---- L1: h1 = relu(x @ sparse(W1*C1) + b1), 2 rows/block, x read exactly once ----
// x staged via global_load_lds width-16 (round-5 measured-good state).
__global__ __launch_bounds__(256) void layer1_sparse(
    const float* __restrict__ x, const unsigned* __restrict__ packed,
    const float* __restrict__ b1, unsigned short* __restrict__ h1)
{
  __shared__ __align__(16) float xs[2*4096];
  const int t = threadIdx.x;
  const long m0 = (long)blockIdx.x * 2;
  const char* src = (const char*)(x + m0*4096);
  #pragma unroll
  for (int i = 0; i < 8; ++i) {
    int seg = t + i*256;                       // 0..2047, 16B each
    gload_lds16(src + (size_t)seg*16, (char*)xs + (size_t)seg*16);
  }
  __syncthreads();
  for (int e = t; e < 2*196; e += 256) {
    int row = (e >= 196) ? 1 : 0;
    int col = e - row*196;
    const float* xr = xs + row*4096;
    float acc = b1[col];
    #pragma unroll
    for (int i = 0; i < 21; ++i) {
      unsigned p = packed[col*21 + i];          // L1-hot 16.5 KB table
      acc += xr[p >> 16] * bf2f((unsigned short)(p & 0xffffu));
    }
    h1[(m0 + row)*256 + col] = f2bf(fmaxf(acc, 0.f));
  }
}

// ---- MX-fp8 MFMA GEMM: C = act(A[M,K] * Bt[N,K]^T + bias) ----
// R6-verified structure (single-buffered, (5g+r)&7 swizzle, full-line
// gload_lds staging, 4 waves as n-slots, FM=8 rows/wave), generalized over
// FN (wave n-tiles). Confirmed model: LDS-read bytes/work = (FM+FN)/(FM*FN);
// conflicts scale with total reads (R6: 8.39M -> 6.29M, exactly 0.75x).
// Round-9 change: gemm<1> goes FN=8 (wave 128x128, block 128x512, 80KB
// dynamic LDS, 2 blocks/CU = same 8 waves/CU) -> 33% fewer fragment reads
// per FLOP. gemm<0> keeps FN=4 (N=2048 at FN=8 would leave 1 block/CU --
// R7's failure regime). Fragment formulas identical -> bitwise-same acc.
// ACT 0: relu -> fp8 x2^6 (LDS repack, stride BN+16); ACT 1: sigmoid -> f32.
template<int ACT, int FN>
__global__ __launch_bounds__(256, 2) void gemm_fp8(
    const unsigned char* __restrict__ A, const unsigned char* __restrict__ Bt,
    const float* __restrict__ bias, void* __restrict__ Cptr, int K, int ldC)
{
  constexpr int BM = 128, BK = 128, FM = 8;
  constexpr int WN = FN * 16;            // wave n-width
  constexpr int BN = 4 * WN;             // block n-width (4 waves)
  constexpr int BROUNDS = BN / 32;       // B stage rounds (segs = BN*8)
  extern __shared__ __align__(16) unsigned char smem[];
  unsigned char* As = smem;              // 16KB: 128 rows x 128B
  unsigned char* Bs = smem + 16384;      // BN rows x 128B
  const int tid  = threadIdx.x;
  const int lane = tid & 63;
  const int w    = tid >> 6;             // wave n-slot 0..3
  const int q = lane >> 4, l16 = lane & 15;
  const long m0 = (long)blockIdx.x * BM;
  const long n0 = (long)blockIdx.y * BN;

  f32x4 acc[FM][FN] = {};

  for (int k0 = 0; k0 < K; k0 += BK) {
    #pragma unroll
    for (int it = 0; it < 4; ++it) {
      int seg = tid + it*256;
      int row = seg >> 3;
      int g   = (5*(seg & 7) + 3*row) & 7;
      gload_lds16(A + (m0 + row)*(long)K + k0 + g*16, As + seg*16);
    }
    #pragma unroll
    for (int it = 0; it < BROUNDS; ++it) {
      int seg = tid + it*256;
      int row = seg >> 3;
      int g   = (5*(seg & 7) + 3*row) & 7;
      gload_lds16(Bt + (n0 + row)*(long)K + k0 + g*16, Bs + seg*16);
    }
    __syncthreads();

    // fragment: lane holds k = q*32..q*32+31 of its row (slots c0, c0+5)
    i32x8 b[FN];
    #pragma unroll
    for (int j = 0; j < FN; ++j) {
      int r = w*WN + j*16 + l16;
      const uint4* p = (const uint4*)(Bs + r*BK);
      int c0 = (2*q + r) & 7;
      union { uint4 v[2]; i32x8 f; } u;
      u.v[0] = p[c0];
      u.v[1] = p[(c0 + 5) & 7];
      b[j] = u.f;
    }
    #pragma unroll
    for (int i = 0; i < FM; ++i) {
      int r = i*16 + l16;
      const uint4* p = (const uint4*)(As + r*BK);
      int c0 = (2*q + r) & 7;
      union { uint4 v[2]; i32x8 f; } u;
      u.v[0] = p[c0];
      u.v[1] = p[(c0 + 5) & 7];
      i32x8 a = u.f;
      #pragma unroll
      for (int j = 0; j < FN; ++j)
        acc[i][j] = __builtin_amdgcn_mfma_scale_f32_16x16x128_f8f6f4(
            a, b[j], acc[i][j], 0, 0, 0, E8M0_ACT, 0, E8M0_W);
    }
    __syncthreads();
  }

  // epilogue: D col = lane&15, row = (lane>>4)*4 + r  [m89/m91 layout]
  if constexpr (ACT == 0) {
    // relu -> fp8 x2^6, repack via smem (row stride BN+16: 16B-aligned,
    // odd multiple of 16 -> breaks 256B bank alias). 128 x (BN+16) bytes.
    constexpr int ST = BN + 16;
    #pragma unroll
    for (int j = 0; j < FN; ++j) {
      int cl = w*WN + j*16 + l16;
      float bv = bias[n0 + cl];
      #pragma unroll
      for (int i = 0; i < FM; ++i) {
        #pragma unroll
        for (int r = 0; r < 4; ++r) {
          int rl = i*16 + q*4 + r;
          smem[rl*ST + cl] = f2fp8(fmaxf(acc[i][j][r] + bv, 0.f) * ACT_SCALE);
        }
      }
    }
    __syncthreads();
    unsigned char* C = (unsigned char*)Cptr;
    #pragma unroll
    for (int it = 0; it < BN/32; ++it) {
      int seg = tid + it*256;           // 128 rows x BN/16 chunks
      int row = seg / (BN/16), ch = seg % (BN/16);
      *(uint4*)(C + (m0 + row)*(long)ldC + n0 + ch*16) =
          *(const uint4*)(smem + row*ST + ch*16);
    }
  } else {
    float* C = (float*)Cptr;
    #pragma unroll
    for (int j = 0; j < FN; ++j) {
      long col = n0 + w*WN + j*16 + l16;
      float bv = bias[col];
      #pragma unroll
      for (int i = 0; i < FM; ++i) {
        #pragma unroll
        for (int r = 0; r < 4; ++r) {
          long row = m0 + i*16 + q*4 + r;
          float v = acc[i][j][r] + bv;
          C[row*(long)ldC + col] = 1.f / (1.f + __expf(-v));
        }
      }
    }
  }
}

// ---- fused L2+L3+L4+L5: h1[8 rows] -> d1 (fp8 x2^6), all intermediates in LDS ----
// 8 rows/block, 512 threads (round-8 banked state): W3/W4/Wd1 loaded once per
// block for 8 rows; ~48KB LDS -> 3 blocks x 8 waves = 24 waves/CU.
__global__ __launch_bounds__(512) void layer2345(
    const unsigned short* __restrict__ h1,
    const float* __restrict__ W2, const float* __restrict__ C2, const float* __restrict__ b2,
    const float* __restrict__ W3, const float* __restrict__ b3,
    const float* __restrict__ W4, const float* __restrict__ b4,
    const float* __restrict__ Wd1, const float* __restrict__ bd1,
    unsigned char* __restrict__ d1)
{
  __shared__ float h1s[8][200];
  __shared__ float h2s[8][10];
  __shared__ float h3s[8][1024];
  __shared__ float part[8][256];   // [kg][row*32+n]
  __shared__ float zs[8][32];
  const int t = threadIdx.x;               // 0..511
  const int w = t >> 6, l = t & 63;        // wave 0..7
  const long m0 = (long)blockIdx.x * 8;

  for (int e = t; e < 8*196; e += 512) {
    int row = e / 196, col = e - row*196;
    h1s[row][col] = bf2f(h1[(m0 + row)*256 + col]);
  }
  __syncthreads();

  // L2: h2[r][10], wave w handles row w (8 waves, 8 rows)
  {
    float acc[10];
    #pragma unroll
    for (int n = 0; n < 10; ++n) acc[n] = 0.f;
    #pragma unroll
    for (int it = 0; it < 4; ++it) {
      int k = l + it*64;
      if (k < 196) {
        float a = h1s[w][k];
        #pragma unroll
        for (int n = 0; n < 10; ++n) acc[n] += a * W2[k*10 + n] * C2[k*10 + n];
      }
    }
    #pragma unroll
    for (int off = 32; off > 0; off >>= 1) {
      #pragma unroll
      for (int n = 0; n < 10; ++n) acc[n] += __shfl_down(acc[n], off, 64);
    }
    if (l < 10) h2s[w][l] = fmaxf(acc[l] + b2[l], 0.f);
  }
  __syncthreads();

  // L3: h3[r][1024]; wave w covers n = w*128 + jj*64 + l; 8 rows/thread
  #pragma unroll
  for (int jj = 0; jj < 2; ++jj) {
    int n = w*128 + jj*64 + l;
    float a0 = b3[n], a1 = a0, a2 = a0, a3 = a0, a4 = a0, a5 = a0, a6 = a0, a7 = a0;
    #pragma unroll
    for (int k = 0; k < 10; ++k) {
      float wv = W3[k*1024 + n];
      a0 += h2s[0][k]*wv; a1 += h2s[1][k]*wv;
      a2 += h2s[2][k]*wv; a3 += h2s[3][k]*wv;
      a4 += h2s[4][k]*wv; a5 += h2s[5][k]*wv;
      a6 += h2s[6][k]*wv; a7 += h2s[7][k]*wv;
    }
    h3s[0][n] = fmaxf(a0, 0.f); h3s[1][n] = fmaxf(a1, 0.f);
    h3s[2][n] = fmaxf(a2, 0.f); h3s[3][n] = fmaxf(a3, 0.f);
    h3s[4][n] = fmaxf(a4, 0.f); h3s[5][n] = fmaxf(a5, 0.f);
    h3s[6][n] = fmaxf(a6, 0.f); h3s[7][n] = fmaxf(a7, 0.f);
  }
  __syncthreads();

  // L4: threads 0..255: (kg = t>>5 in 0..7, n = t&31), k = kg*128..+127
  if (t < 256) {
    int n = t & 31, kg = t >> 5;
    float a0 = 0.f, a1 = 0.f, a2 = 0.f, a3 = 0.f,
          a4 = 0.f, a5 = 0.f, a6 = 0.f, a7 = 0.f;
    for (int k = kg*128; k < kg*128 + 128; ++k) {
      float wv = W4[k*32 + n];
      a0 += h3s[0][k]*wv; a1 += h3s[1][k]*wv;
      a2 += h3s[2][k]*wv; a3 += h3s[3][k]*wv;
      a4 += h3s[4][k]*wv; a5 += h3s[5][k]*wv;
      a6 += h3s[6][k]*wv; a7 += h3s[7][k]*wv;
    }
    part[kg][0*32 + n] = a0; part[kg][1*32 + n] = a1;
    part[kg][2*32 + n] = a2; part[kg][3*32 + n] = a3;
    part[kg][4*32 + n] = a4; part[kg][5*32 + n] = a5;
    part[kg][6*32 + n] = a6; part[kg][7*32 + n] = a7;
  }
  __syncthreads();
  if (t < 256) {
    float s = 0.f;
    #pragma unroll
    for (int kg = 0; kg < 8; ++kg) s += part[kg][t];
    zs[t >> 5][t & 31] = fmaxf(s + b4[t & 31], 0.f);
  }
  __syncthreads();

  // L5: d1[r][1024] fp8 x2^6; wave w covers n = w*128 + jj*64 + l
  #pragma unroll
  for (int jj = 0; jj < 2; ++jj) {
    int n = w*128 + jj*64 + l;
    float a0 = bd1[n], a1 = a0, a2 = a0, a3 = a0, a4 = a0, a5 = a0, a6 = a0, a7 = a0;
    #pragma unroll
    for (int k = 0; k < 32; ++k) {
      float wv = Wd1[k*1024 + n];
      a0 += zs[0][k]*wv; a1 += zs[1][k]*wv;
      a2 += zs[2][k]*wv; a3 += zs[3][k]*wv;
      a4 += zs[4][k]*wv; a5 += zs[5][k]*wv;
      a6 += zs[6][k]*wv; a7 += zs[7][k]*wv;
    }
    d1[(m0 + 0)*1024 + n] = f2fp8(fmaxf(a0, 0.f) * ACT_SCALE);
    d1[(m0 + 1)*1024 + n] = f2fp8(fmaxf(a1, 0.f) * ACT_SCALE);
    d1[(m0 + 2)*1024 + n] = f2fp8(fmaxf(a2, 0.f) * ACT_SCALE);
    d1[(m0 + 3)*1024 + n] = f2fp8(fmaxf(a3, 0.f) * ACT_SCALE);
    d1[(m0 + 4)*1024 + n] = f2fp8(fmaxf(a4, 0.f) * ACT_SCALE);
    d1[(m0 + 5)*1024 + n] = f2fp8(fmaxf(a5, 0.f) * ACT_SCALE);
    d1[(m0 + 6)*1024 + n] = f2fp8(fmaxf(a6, 0.f) * ACT_SCALE);
    d1[(m0 + 7)*1024 + n] = f2fp8(fmaxf(a7, 0.f) * ACT_SCALE);
  }
}

extern "C" void kernel_launch(void* const* d_in, const int* in_sizes, int n_in,
                              void* d_out, int out_size, void* d_ws, size_t ws_size,
                              hipStream_t stream)
{
  (void)in_sizes; (void)n_in; (void)out_size; (void)ws_size;
  const float* x   = (const float*)d_in[0];
  const float* C1  = (const float*)d_in[1];
  const float* W1  = (const float*)d_in[2];
  const float* b1  = (const float*)d_in[3];
  const float* C2  = (const float*)d_in[4];
  const float* W2  = (const float*)d_in[5];
  const float* b2  = (const float*)d_in[6];
  const float* W3  = (const float*)d_in[7];
  const float* b3  = (const float*)d_in[8];
  const float* W4  = (const float*)d_in[9];
  const float* b4  = (const float*)d_in[10];
  const float* Wd1 = (const float*)d_in[11];
  const float* bd1 = (const float*)d_in[12];
  const float* Wd2 = (const float*)d_in[13];
  const float* bd2 = (const float*)d_in[14];
  const float* Wd3 = (const float*)d_in[15];
  const float* bd3 = (const float*)d_in[16];
  float* out = (float*)d_out;

  char* ws = (char*)d_ws;
  size_t off = 0;
  auto alloc = [&](size_t bytes) -> void* {
    void* p = ws + off; off += (bytes + 255) & ~(size_t)255; return p;
  };
  unsigned char* Wt2 = (unsigned char*)alloc((size_t)2048*1024);   // Wd2^T fp8 x16
  unsigned char* Wt3 = (unsigned char*)alloc((size_t)4096*2048);   // Wd3^T fp8 x16
  unsigned*      pk  = (unsigned*)     alloc((size_t)196*21*4);    // packed sparse W1C1
  unsigned short* h1 = (unsigned short*)alloc((size_t)8192*256*2); // bf16
  unsigned char*  d1 = (unsigned char*) alloc((size_t)8192*1024);  // fp8 x2^6
  unsigned char*  d2 = (unsigned char*) alloc((size_t)8192*2048);  // fp8 x2^6

  // opt-in dynamic LDS (gemm<0,4>: 48KB, gemm<1,8>: 80KB)
  static int attr_set = 0;
  if (!attr_set) {
    hipFuncSetAttribute((const void*)gemm_fp8<0,4>,
                        hipFuncAttributeMaxDynamicSharedMemorySize, 49152);
    hipFuncSetAttribute((const void*)gemm_fp8<1,8>,
                        hipFuncAttributeMaxDynamicSharedMemorySize, 81920);
    attr_set = 1;
  }

  // prep
  build_sparse<<<dim3(196), 256, 0, stream>>>(C1, W1, pk);
  transpose_fp8<<<dim3(1024/32, 2048/32), 256, 0, stream>>>(Wd2, Wt2, 1024, 2048);
  transpose_fp8<<<dim3(2048/32, 4096/32), 256, 0, stream>>>(Wd3, Wt3, 2048, 4096);

  // L1: h1 = relu(x @ (W1*C1) + b1) — sparse gather, x read once
  layer1_sparse<<<dim3(8192/2), 256, 0, stream>>>(x, pk, b1, h1);
  // L2..L5 fused: 8 rows/block, 512 threads
  layer2345<<<dim3(8192/8), 512, 0, stream>>>(h1, W2, C2, b2, W3, b3, W4, b4,
                                              Wd1, bd1, d1);
  // L6: d2 = relu(d1 @ Wd2 + bd2)  M=8192 N=2048 K=1024  (MX-fp8, 128x256)
  gemm_fp8<0,4><<<dim3(8192/128, 2048/256), 256, 49152, stream>>>(
      d1, Wt2, bd2, d2, 1024, 2048);
  // L7: out = sigmoid(d2 @ Wd3 + bd3)  M=8192 N=4096 K=2048  (MX-fp8, 128x512)
  gemm_fp8<1,8><<<dim3(8192/128, 4096/512), 256, 81920, stream>>>(
      d2, Wt3, bd3, out, 2048, 4096);
}

// Round 10
// 451.899 us; speedup vs baseline: 1.6388x; 1.6388x over previous
//
#include <hip/hip_runtime.h>
#include <hip/hip_fp8.h>
#include <cstdint>
#include <cstddef>

typedef __attribute__((ext_vector_type(4))) float f32x4;
typedef __attribute__((ext_vector_type(8))) int i32x8;

#define DEVINL __device__ __forceinline__

DEVINL unsigned short f2bf(float f){
  union { float f; unsigned u; } v; v.f = f;
  unsigned r = v.u + 0x7fffu + ((v.u >> 16) & 1u);  // RNE
  return (unsigned short)(r >> 16);
}
DEVINL float bf2f(unsigned short h){
  union { unsigned u; float f; } v; v.u = ((unsigned)h) << 16;
  return v.f;
}
DEVINL unsigned char f2fp8(float f){
  __hip_fp8_e4m3 t(f);           // OCP e4m3fn, saturating
  return (unsigned char)t.__x;
}
DEVINL void gload_lds16(const void* g, void* l){
  __builtin_amdgcn_global_load_lds((const __attribute__((address_space(1))) void*)g,
                                   (__attribute__((address_space(3))) void*)l, 16, 0, 0);
}

// scale constants: activations stored x2^6, weights x2^4; descale via e8m0 MFMA scales
#define ACT_SCALE 64.0f
#define W_SCALE   16.0f
#define E8M0_ACT  121   // 2^-6
#define E8M0_W    123   // 2^-4

// ---- weight prep: Wt[n][k] = fp8(W[k][n] * 16) ----
__global__ __launch_bounds__(256) void transpose_fp8(
    const float* __restrict__ W, unsigned char* __restrict__ Wt, int K, int N)
{
  __shared__ unsigned char tile[32][33];
  int k0 = blockIdx.x * 32, n0 = blockIdx.y * 32;
  int tx = threadIdx.x & 31, ty = threadIdx.x >> 5;
  #pragma unroll
  for (int i = 0; i < 4; ++i) {
    int k = k0 + ty + 8*i, n = n0 + tx;
    tile[ty + 8*i][tx] = f2fp8(W[(size_t)k*N + n] * W_SCALE);
  }
  __syncthreads();
  #pragma unroll
  for (int i = 0; i < 4; ++i) {
    int n = n0 + ty + 8*i, k = k0 + tx;
    Wt[(size_t)n*K + k] = tile[tx][ty + 8*i];
  }
}

// ---- L1 prep: compact knn mask column j -> 21 packed (idx<<16 | bf16(W1)) ----
__global__ __launch_bounds__(256) void build_sparse(
    const float* __restrict__ C1, const float* __restrict__ W1,
    unsigned* __restrict__ packed)
{
  const int j = blockIdx.x;            // 0..195
  const int w = threadIdx.x >> 6, l = threadIdx.x & 63;
  __shared__ int wcnt[4], wbase[4];
  int cnt = 0;
  #pragma unroll 4
  for (int it = 0; it < 16; ++it) {
    int k = w*1024 + it*64 + l;
    float c = C1[(size_t)k*196 + j];
    unsigned long long m = __ballot(c != 0.f);
    cnt += (int)__popcll(m);
  }
  if (l == 0) wcnt[w] = cnt;
  __syncthreads();
  if (threadIdx.x < 21) packed[j*21 + threadIdx.x] = 0;  // safety vs poison
  if (threadIdx.x == 0) {
    int b = 0;
    #pragma unroll
    for (int i = 0; i < 4; ++i) { wbase[i] = b; b += wcnt[i]; }
  }
  __syncthreads();
  int base = wbase[w];
  #pragma unroll 4
  for (int it = 0; it < 16; ++it) {
    int k = w*1024 + it*64 + l;
    float c = C1[(size_t)k*196 + j];
    unsigned long long m = __ballot(c != 0.f);
    if (c != 0.f) {
      int pos = base + (int)__popcll(m & ((1ull << l) - 1ull));
      if (pos < 21)
        packed[j*21 + pos] = ((unsigned)k << 16)
                           | (unsigned)f2bf(W1[(size_t)k*196 + j] * c);
    }
    base += (int)__popcll(m);
  }
}

// ---- L1: h1 = relu(x @ sparse(W1*C1) + b1), 2 rows/block, x read exactly once ----
// x staged via global_load_lds width-16 (round-5 measured-good state).
__global__ __launch_bounds__(256) void layer1_sparse(
    const float* __restrict__ x, const unsigned* __restrict__ packed,
    const float* __restrict__ b1, unsigned short* __restrict__ h1)
{
  __shared__ __align__(16) float xs[2*4096];
  const int t = threadIdx.x;
  const long m0 = (long)blockIdx.x * 2;
  const char* src = (const char*)(x + m0*4096);
  #pragma unroll
  for (int i = 0; i < 8; ++i) {
    int seg = t + i*256;                       // 0..2047, 16B each
    gload_lds16(src + (size_t)seg*16, (char*)xs + (size_t)seg*16);
  }
  __syncthreads();
  for (int e = t; e < 2*196; e += 256) {
    int row = (e >= 196) ? 1 : 0;
    int col = e - row*196;
    const float* xr = xs + row*4096;
    float acc = b1[col];
    #pragma unroll
    for (int i = 0; i < 21; ++i) {
      unsigned p = packed[col*21 + i];          // L1-hot 16.5 KB table
      acc += xr[p >> 16] * bf2f((unsigned short)(p & 0xffffu));
    }
    h1[(m0 + row)*256 + col] = f2bf(fmaxf(acc, 0.f));
  }
}

// ---- MX-fp8 MFMA GEMM: C = act(A[M,K] * Bt[N,K]^T + bias) ----
// EXACT round-8 banked structure (measured best: ~84us, MfmaUtil 33%):
// 128x256 block tile, per-wave 128x64 (FM=8, FN=4, 4 waves as n-slots),
// single-buffered 48KB static LDS, (5g+r)&7 chunk swizzle, full-line
// gload_lds staging. ~240 regs/wave -> 2 blocks/CU; cross-block wave
// overlap (m114) hides the barrier drain. Measured-closed alternatives:
// R1/R7 dbuf schedules (drain kills prefetch; 1 blk/CU lockstep),
// R2 conflict-free read layout (half-line staging), R9 FN=8 (acc=256
// VGPR -> scratch spill, 637MB fetch). This is the structure's optimum.
// ACT 0: relu -> fp8 x2^6 (LDS repack, stride 272, coalesced 16B stores);
// ACT 1: sigmoid -> fp32. Grid (M/128, N/256), 256 threads.
template<int ACT>
__global__ __launch_bounds__(256, 2) void gemm_fp8(
    const unsigned char* __restrict__ A, const unsigned char* __restrict__ Bt,
    const float* __restrict__ bias, void* __restrict__ Cptr, int K, int ldC)
{
  constexpr int BM = 128, BN = 256, BK = 128;
  constexpr int FM = 8, FN = 4;
  __shared__ __align__(16) unsigned char smem[49152];
  unsigned char* As = smem;             // 16KB: 128 rows x 128B
  unsigned char* Bs = smem + 16384;     // 32KB: 256 rows x 128B
  const int tid  = threadIdx.x;
  const int lane = tid & 63;
  const int w    = tid >> 6;            // wave n-slot 0..3
  const int q = lane >> 4, l16 = lane & 15;
  const long m0 = (long)blockIdx.x * BM;
  const long n0 = (long)blockIdx.y * BN;

  f32x4 acc[FM][FN] = {};

  for (int k0 = 0; k0 < K; k0 += BK) {
    #pragma unroll
    for (int it = 0; it < 4; ++it) {
      int seg = tid + it*256;
      int row = seg >> 3;
      int g   = (5*(seg & 7) + 3*row) & 7;
      gload_lds16(A + (m0 + row)*(long)K + k0 + g*16, As + seg*16);
    }
    #pragma unroll
    for (int it = 0; it < 8; ++it) {
      int seg = tid + it*256;
      int row = seg >> 3;
      int g   = (5*(seg & 7) + 3*row) & 7;
      gload_lds16(Bt + (n0 + row)*(long)K + k0 + g*16, Bs + seg*16);
    }
    __syncthreads();

    // fragment: lane holds k = q*32..q*32+31 of its row (slots c0, c0+5)
    i32x8 b[FN];
    #pragma unroll
    for (int j = 0; j < FN; ++j) {
      int r = w*64 + j*16 + l16;
      const uint4* p = (const uint4*)(Bs + r*BK);
      int c0 = (2*q + r) & 7;
      union { uint4 v[2]; i32x8 f; } u;
      u.v[0] = p[c0];
      u.v[1] = p[(c0 + 5) & 7];
      b[j] = u.f;
    }
    #pragma unroll
    for (int i = 0; i < FM; ++i) {
      int r = i*16 + l16;
      const uint4* p = (const uint4*)(As + r*BK);
      int c0 = (2*q + r) & 7;
      union { uint4 v[2]; i32x8 f; } u;
      u.v[0] = p[c0];
      u.v[1] = p[(c0 + 5) & 7];
      i32x8 a = u.f;
      #pragma unroll
      for (int j = 0; j < FN; ++j)
        acc[i][j] = __builtin_amdgcn_mfma_scale_f32_16x16x128_f8f6f4(
            a, b[j], acc[i][j], 0, 0, 0, E8M0_ACT, 0, E8M0_W);
    }
    __syncthreads();
  }

  // epilogue: D col = lane&15, row = (lane>>4)*4 + r  [m89/m91 layout]
  if constexpr (ACT == 0) {
    // relu -> fp8 x2^6, repack via smem (row stride 272 = 17x16: aligned,
    // breaks 256-alias). 128 rows x 272 = 34.8KB <= 48KB buffer.
    #pragma unroll
    for (int j = 0; j < FN; ++j) {
      int cl = w*64 + j*16 + l16;
      float bv = bias[n0 + cl];
      #pragma unroll
      for (int i = 0; i < FM; ++i) {
        #pragma unroll
        for (int r = 0; r < 4; ++r) {
          int rl = i*16 + q*4 + r;
          smem[rl*272 + cl] = f2fp8(fmaxf(acc[i][j][r] + bv, 0.f) * ACT_SCALE);
        }
      }
    }
    __syncthreads();
    unsigned char* C = (unsigned char*)Cptr;
    #pragma unroll
    for (int it = 0; it < 8; ++it) {
      int seg = tid + it*256;           // 2048 segs: 128 rows x 16 chunks
      int row = seg >> 4, ch = seg & 15;
      *(uint4*)(C + (m0 + row)*(long)ldC + n0 + ch*16) =
          *(const uint4*)(smem + row*272 + ch*16);
    }
  } else {
    float* C = (float*)Cptr;
    #pragma unroll
    for (int j = 0; j < FN; ++j) {
      long col = n0 + w*64 + j*16 + l16;
      float bv = bias[col];
      #pragma unroll
      for (int i = 0; i < FM; ++i) {
        #pragma unroll
        for (int r = 0; r < 4; ++r) {
          long row = m0 + i*16 + q*4 + r;
          float v = acc[i][j][r] + bv;
          C[row*(long)ldC + col] = 1.f / (1.f + __expf(-v));
        }
      }
    }
  }
}

// ---- fused L2+L3+L4+L5: h1[8 rows] -> d1 (fp8 x2^6), all intermediates in LDS ----
// 8 rows/block, 512 threads (round-8 banked state). Round-10 change (one
// variable): L4 splits the 8 rows across ALL 512 threads (t<256: rows 0-3,
// t>=256: rows 4-7) -> per-thread dependent-FMA chain in the longest phase
// halves; same kg/n mapping, same part[8][256], same per-row 8x128 partial
// tree -> bit-identical sums. W4 values L2-broadcast to both halves.
__global__ __launch_bounds__(512) void layer2345(
    const unsigned short* __restrict__ h1,
    const float* __restrict__ W2, const float* __restrict__ C2, const float* __restrict__ b2,
    const float* __restrict__ W3, const float* __restrict__ b3,
    const float* __restrict__ W4, const float* __restrict__ b4,
    const float* __restrict__ Wd1, const float* __restrict__ bd1,
    unsigned char* __restrict__ d1)
{
  __shared__ float h1s[8][200];
  __shared__ float h2s[8][10];
  __shared__ float h3s[8][1024];
  __shared__ float part[8][256];   // [kg][row*32+n]
  __shared__ float zs[8][32];
  const int t = threadIdx.x;               // 0..511
  const int w = t >> 6, l = t & 63;        // wave 0..7
  const long m0 = (long)blockIdx.x * 8;

  for (int e = t; e < 8*196; e += 512) {
    int row = e / 196, col = e - row*196;
    h1s[row][col] = bf2f(h1[(m0 + row)*256 + col]);
  }
  __syncthreads();

  // L2: h2[r][10], wave w handles row w (8 waves, 8 rows)
  {
    float acc[10];
    #pragma unroll
    for (int n = 0; n < 10; ++n) acc[n] = 0.f;
    #pragma unroll
    for (int it = 0; it < 4; ++it) {
      int k = l + it*64;
      if (k < 196) {
        float a = h1s[w][k];
        #pragma unroll
        for (int n = 0; n < 10; ++n) acc[n] += a * W2[k*10 + n] * C2[k*10 + n];
      }
    }
    #pragma unroll
    for (int off = 32; off > 0; off >>= 1) {
      #pragma unroll
      for (int n = 0; n < 10; ++n) acc[n] += __shfl_down(acc[n], off, 64);
    }
    if (l < 10) h2s[w][l] = fmaxf(acc[l] + b2[l], 0.f);
  }
  __syncthreads();

  // L3: h3[r][1024]; wave w covers n = w*128 + jj*64 + l; 8 rows/thread
  #pragma unroll
  for (int jj = 0; jj < 2; ++jj) {
    int n = w*128 + jj*64 + l;
    float a0 = b3[n], a1 = a0, a2 = a0, a3 = a0, a4 = a0, a5 = a0, a6 = a0, a7 = a0;
    #pragma unroll
    for (int k = 0; k < 10; ++k) {
      float wv = W3[k*1024 + n];
      a0 += h2s[0][k]*wv; a1 += h2s[1][k]*wv;
      a2 += h2s[2][k]*wv; a3 += h2s[3][k]*wv;
      a4 += h2s[4][k]*wv; a5 += h2s[5][k]*wv;
      a6 += h2s[6][k]*wv; a7 += h2s[7][k]*wv;
    }
    h3s[0][n] = fmaxf(a0, 0.f); h3s[1][n] = fmaxf(a1, 0.f);
    h3s[2][n] = fmaxf(a2, 0.f); h3s[3][n] = fmaxf(a3, 0.f);
    h3s[4][n] = fmaxf(a4, 0.f); h3s[5][n] = fmaxf(a5, 0.f);
    h3s[6][n] = fmaxf(a6, 0.f); h3s[7][n] = fmaxf(a7, 0.f);
  }
  __syncthreads();

  // L4: all 512 threads: tt = t&255 -> (kg = tt>>5, n = tt&31); t<256 does
  // rows 0-3, t>=256 rows 4-7. Same 8x128 per-row partial tree as before.
  {
    int tt = t & 255;
    int n = tt & 31, kg = tt >> 5;
    int r0 = (t >> 8) * 4;               // 0 or 4
    float a0 = 0.f, a1 = 0.f, a2 = 0.f, a3 = 0.f;
    for (int k = kg*128; k < kg*128 + 128; ++k) {
      float wv = W4[k*32 + n];
      a0 += h3s[r0+0][k]*wv; a1 += h3s[r0+1][k]*wv;
      a2 += h3s[r0+2][k]*wv; a3 += h3s[r0+3][k]*wv;
    }
    part[kg][(r0+0)*32 + n] = a0; part[kg][(r0+1)*32 + n] = a1;
    part[kg][(r0+2)*32 + n] = a2; part[kg][(r0+3)*32 + n] = a3;
  }
  __syncthreads();
  if (t < 256) {
    float s = 0.f;
    #pragma unroll
    for (int kg = 0; kg < 8; ++kg) s += part[kg][t];
    zs[t >> 5][t & 31] = fmaxf(s + b4[t & 31], 0.f);
  }
  __syncthreads();

  // L5: d1[r][1024] fp8 x2^6; wave w covers n = w*128 + jj*64 + l
  #pragma unroll
  for (int jj = 0; jj < 2; ++jj) {
    int n = w*128 + jj*64 + l;
    float a0 = bd1[n], a1 = a0, a2 = a0, a3 = a0, a4 = a0, a5 = a0, a6 = a0, a7 = a0;
    #pragma unroll
    for (int k = 0; k < 32; ++k) {
      float wv = Wd1[k*1024 + n];
      a0 += zs[0][k]*wv; a1 += zs[1][k]*wv;
      a2 += zs[2][k]*wv; a3 += zs[3][k]*wv;
      a4 += zs[4][k]*wv; a5 += zs[5][k]*wv;
      a6 += zs[6][k]*wv; a7 += zs[7][k]*wv;
    }
    d1[(m0 + 0)*1024 + n] = f2fp8(fmaxf(a0, 0.f) * ACT_SCALE);
    d1[(m0 + 1)*1024 + n] = f2fp8(fmaxf(a1, 0.f) * ACT_SCALE);
    d1[(m0 + 2)*1024 + n] = f2fp8(fmaxf(a2, 0.f) * ACT_SCALE);
    d1[(m0 + 3)*1024 + n] = f2fp8(fmaxf(a3, 0.f) * ACT_SCALE);
    d1[(m0 + 4)*1024 + n] = f2fp8(fmaxf(a4, 0.f) * ACT_SCALE);
    d1[(m0 + 5)*1024 + n] = f2fp8(fmaxf(a5, 0.f) * ACT_SCALE);
    d1[(m0 + 6)*1024 + n] = f2fp8(fmaxf(a6, 0.f) * ACT_SCALE);
    d1[(m0 + 7)*1024 + n] = f2fp8(fmaxf(a7, 0.f) * ACT_SCALE);
  }
}

extern "C" void kernel_launch(void* const* d_in, const int* in_sizes, int n_in,
                              void* d_out, int out_size, void* d_ws, size_t ws_size,
                              hipStream_t stream)
{
  (void)in_sizes; (void)n_in; (void)out_size; (void)ws_size;
  const float* x   = (const float*)d_in[0];
  const float* C1  = (const float*)d_in[1];
  const float* W1  = (const float*)d_in[2];
  const float* b1  = (const float*)d_in[3];
  const float* C2  = (const float*)d_in[4];
  const float* W2  = (const float*)d_in[5];
  const float* b2  = (const float*)d_in[6];
  const float* W3  = (const float*)d_in[7];
  const float* b3  = (const float*)d_in[8];
  const float* W4  = (const float*)d_in[9];
  const float* b4  = (const float*)d_in[10];
  const float* Wd1 = (const float*)d_in[11];
  const float* bd1 = (const float*)d_in[12];
  const float* Wd2 = (const float*)d_in[13];
  const float* bd2 = (const float*)d_in[14];
  const float* Wd3 = (const float*)d_in[15];
  const float* bd3 = (const float*)d_in[16];
  float* out = (float*)d_out;

  char* ws = (char*)d_ws;
  size_t off = 0;
  auto alloc = [&](size_t bytes) -> void* {
    void* p = ws + off; off += (bytes + 255) & ~(size_t)255; return p;
  };
  unsigned char* Wt2 = (unsigned char*)alloc((size_t)2048*1024);   // Wd2^T fp8 x16
  unsigned char* Wt3 = (unsigned char*)alloc((size_t)4096*2048);   // Wd3^T fp8 x16
  unsigned*      pk  = (unsigned*)     alloc((size_t)196*21*4);    // packed sparse W1C1
  unsigned short* h1 = (unsigned short*)alloc((size_t)8192*256*2); // bf16
  unsigned char*  d1 = (unsigned char*) alloc((size_t)8192*1024);  // fp8 x2^6
  unsigned char*  d2 = (unsigned char*) alloc((size_t)8192*2048);  // fp8 x2^6

  // prep
  build_sparse<<<dim3(196), 256, 0, stream>>>(C1, W1, pk);
  transpose_fp8<<<dim3(1024/32, 2048/32), 256, 0, stream>>>(Wd2, Wt2, 1024, 2048);
  transpose_fp8<<<dim3(2048/32, 4096/32), 256, 0, stream>>>(Wd3, Wt3, 2048, 4096);

  // L1: h1 = relu(x @ (W1*C1) + b1) — sparse gather, x read once
  layer1_sparse<<<dim3(8192/2), 256, 0, stream>>>(x, pk, b1, h1);
  // L2..L5 fused: 8 rows/block, 512 threads
  layer2345<<<dim3(8192/8), 512, 0, stream>>>(h1, W2, C2, b2, W3, b3, W4, b4,
                                              Wd1, bd1, d1);
  // L6: d2 = relu(d1 @ Wd2 + bd2)  M=8192 N=2048 K=1024  (MX-fp8, 128x256)
  gemm_fp8<0><<<dim3(8192/128, 2048/256), 256, 0, stream>>>(
      d1, Wt2, bd2, d2, 1024, 2048);
  // L7: out = sigmoid(d2 @ Wd3 + bd3)  M=8192 N=4096 K=2048  (MX-fp8, 128x256)
  gemm_fp8<1><<<dim3(8192/128, 4096/256), 256, 0, stream>>>(
      d2, Wt3, bd3, out, 2048, 4096);
}

// Round 11
// 450.819 us; speedup vs baseline: 1.6427x; 1.0024x over previous
//
#include <hip/hip_runtime.h>
#include <hip/hip_fp8.h>
#include <cstdint>
#include <cstddef>

typedef __attribute__((ext_vector_type(4))) float f32x4;
typedef __attribute__((ext_vector_type(8))) int i32x8;

#define DEVINL __device__ __forceinline__

DEVINL unsigned short f2bf(float f){
  union { float f; unsigned u; } v; v.f = f;
  unsigned r = v.u + 0x7fffu + ((v.u >> 16) & 1u);  // RNE
  return (unsigned short)(r >> 16);
}
DEVINL float bf2f(unsigned short h){
  union { unsigned u; float f; } v; v.u = ((unsigned)h) << 16;
  return v.f;
}
DEVINL unsigned char f2fp8(float f){
  __hip_fp8_e4m3 t(f);           // OCP e4m3fn, saturating
  return (unsigned char)t.__x;
}
DEVINL void gload_lds16(const void* g, void* l){
  __builtin_amdgcn_global_load_lds((const __attribute__((address_space(1))) void*)g,
                                   (__attribute__((address_space(3))) void*)l, 16, 0, 0);
}

// scale constants: activations stored x2^6, weights x2^4; descale via e8m0 MFMA scales
#define ACT_SCALE 64.0f
#define W_SCALE   16.0f
#define E8M0_ACT  121   // 2^-6
#define E8M0_W    123   // 2^-4

// ---- merged prep: build_sparse (196 blocks) + both fp8 weight transposes ----
// Round-11 change: one launch instead of three (removes 2 serial launch gaps;
// build_sparse's latency-bound blocks co-run with transpose BW work), and the
// transpose is vectorized: 64x64 tiles, float4 loads (16B/lane), packed u32
// LDS writes, uchar4 stores (64B per 16-lane group). Same fp8(W[k][n]*16)
// values to the same Wt[n*K+k] addresses -> bit-identical outputs.
// grid: [0,196) build_sparse j=bid; [196,708) Wd2 tiles; [708,2756) Wd3 tiles.
__global__ __launch_bounds__(256) void prep_all(
    const float* __restrict__ C1, const float* __restrict__ W1,
    unsigned* __restrict__ packed,
    const float* __restrict__ Wd2, unsigned char* __restrict__ Wt2,
    const float* __restrict__ Wd3, unsigned char* __restrict__ Wt3)
{
  __shared__ unsigned char tile[64*68];    // 4.25KB (transpose branch)
  __shared__ int wcnt[4], wbase[4];        // (sparse branch)
  const int bid = blockIdx.x;
  const int t = threadIdx.x;

  if (bid < 196) {
    // ---- build_sparse, logic byte-identical to the split kernel ----
    const int j = bid;
    const int w = t >> 6, l = t & 63;
    int cnt = 0;
    #pragma unroll 4
    for (int it = 0; it < 16; ++it) {
      int k = w*1024 + it*64 + l;
      float c = C1[(size_t)k*196 + j];
      unsigned long long m = __ballot(c != 0.f);
      cnt += (int)__popcll(m);
    }
    if (l == 0) wcnt[w] = cnt;
    __syncthreads();
    if (t < 21) packed[j*21 + t] = 0;  // safety vs poison
    if (t == 0) {
      int b = 0;
      #pragma unroll
      for (int i = 0; i < 4; ++i) { wbase[i] = b; b += wcnt[i]; }
    }
    __syncthreads();
    int base = wbase[w];
    #pragma unroll 4
    for (int it = 0; it < 16; ++it) {
      int k = w*1024 + it*64 + l;
      float c = C1[(size_t)k*196 + j];
      unsigned long long m = __ballot(c != 0.f);
      if (c != 0.f) {
        int pos = base + (int)__popcll(m & ((1ull << l) - 1ull));
        if (pos < 21)
          packed[j*21 + pos] = ((unsigned)k << 16)
                             | (unsigned)f2bf(W1[(size_t)k*196 + j] * c);
      }
      base += (int)__popcll(m);
    }
  } else {
    // ---- fp8 transpose, 64x64 tile ----
    const float* W; unsigned char* Wt; int K, N, tid;
    if (bid < 196 + 512) { W = Wd2; Wt = Wt2; K = 1024; N = 2048; tid = bid - 196; }
    else                 { W = Wd3; Wt = Wt3; K = 2048; N = 4096; tid = bid - 708; }
    const int ktiles = K >> 6;
    const int k0 = (tid % ktiles) * 64, n0 = (tid / ktiles) * 64;
    const int lr = t >> 4, lc4 = (t & 15) * 4;
    // load 4 rows-of-16-threads x float4, convert, packed u32 LDS write
    #pragma unroll
    for (int it = 0; it < 4; ++it) {
      int kl = lr + it*16;
      float4 v = *(const float4*)(W + (size_t)(k0 + kl)*N + n0 + lc4);
      unsigned u = (unsigned)f2fp8(v.x * W_SCALE)
                 | ((unsigned)f2fp8(v.y * W_SCALE) << 8)
                 | ((unsigned)f2fp8(v.z * W_SCALE) << 16)
                 | ((unsigned)f2fp8(v.w * W_SCALE) << 24);
      *(unsigned*)(tile + kl*68 + lc4) = u;
    }
    __syncthreads();
    // store: thread covers 4 consecutive k for its n -> uchar4 (u32) store
    #pragma unroll
    for (int it = 0; it < 4; ++it) {
      int nl = lr + it*16;
      unsigned u = (unsigned)tile[(lc4+0)*68 + nl]
                 | ((unsigned)tile[(lc4+1)*68 + nl] << 8)
                 | ((unsigned)tile[(lc4+2)*68 + nl] << 16)
                 | ((unsigned)tile[(lc4+3)*68 + nl] << 24);
      *(unsigned*)(Wt + (size_t)(n0 + nl)*K + k0 + lc4) = u;
    }
  }
}

// ---- L1: h1 = relu(x @ sparse(W1*C1) + b1), 2 rows/block, x read exactly once ----
// x staged via global_load_lds width-16 (round-5 measured-good state).
__global__ __launch_bounds__(256) void layer1_sparse(
    const float* __restrict__ x, const unsigned* __restrict__ packed,
    const float* __restrict__ b1, unsigned short* __restrict__ h1)
{
  __shared__ __align__(16) float xs[2*4096];
  const int t = threadIdx.x;
  const long m0 = (long)blockIdx.x * 2;
  const char* src = (const char*)(x + m0*4096);
  #pragma unroll
  for (int i = 0; i < 8; ++i) {
    int seg = t + i*256;                       // 0..2047, 16B each
    gload_lds16(src + (size_t)seg*16, (char*)xs + (size_t)seg*16);
  }
  __syncthreads();
  for (int e = t; e < 2*196; e += 256) {
    int row = (e >= 196) ? 1 : 0;
    int col = e - row*196;
    const float* xr = xs + row*4096;
    float acc = b1[col];
    #pragma unroll
    for (int i = 0; i < 21; ++i) {
      unsigned p = packed[col*21 + i];          // L1-hot 16.5 KB table
      acc += xr[p >> 16] * bf2f((unsigned short)(p & 0xffffu));
    }
    h1[(m0 + row)*256 + col] = f2bf(fmaxf(acc, 0.f));
  }
}

// ---- MX-fp8 MFMA GEMM: C = act(A[M,K] * Bt[N,K]^T + bias) ----
// EXACT round-8 banked structure (measured best: ~84us, MfmaUtil 33%):
// 128x256 block tile, per-wave 128x64 (FM=8, FN=4, 4 waves as n-slots),
// single-buffered 48KB static LDS, (5g+r)&7 chunk swizzle, full-line
// gload_lds staging. ~240 regs/wave -> 2 blocks/CU; cross-block wave
// overlap (m114) hides the barrier drain. Measured-closed alternatives:
// R1/R7 dbuf schedules (drain kills prefetch; 1 blk/CU lockstep),
// R2 conflict-free read layout (half-line staging), R9 FN=8 (acc=256
// VGPR -> scratch spill, 637MB fetch). This is the structure's optimum.
// ACT 0: relu -> fp8 x2^6 (LDS repack, stride 272, coalesced 16B stores);
// ACT 1: sigmoid -> fp32. Grid (M/128, N/256), 256 threads.
template<int ACT>
__global__ __launch_bounds__(256, 2) void gemm_fp8(
    const unsigned char* __restrict__ A, const unsigned char* __restrict__ Bt,
    const float* __restrict__ bias, void* __restrict__ Cptr, int K, int ldC)
{
  constexpr int BM = 128, BN = 256, BK = 128;
  constexpr int FM = 8, FN = 4;
  __shared__ __align__(16) unsigned char smem[49152];
  unsigned char* As = smem;             // 16KB: 128 rows x 128B
  unsigned char* Bs = smem + 16384;     // 32KB: 256 rows x 128B
  const int tid  = threadIdx.x;
  const int lane = tid & 63;
  const int w    = tid >> 6;            // wave n-slot 0..3
  const int q = lane >> 4, l16 = lane & 15;
  const long m0 = (long)blockIdx.x * BM;
  const long n0 = (long)blockIdx.y * BN;

  f32x4 acc[FM][FN] = {};

  for (int k0 = 0; k0 < K; k0 += BK) {
    #pragma unroll
    for (int it = 0; it < 4; ++it) {
      int seg = tid + it*256;
      int row = seg >> 3;
      int g   = (5*(seg & 7) + 3*row) & 7;
      gload_lds16(A + (m0 + row)*(long)K + k0 + g*16, As + seg*16);
    }
    #pragma unroll
    for (int it = 0; it < 8; ++it) {
      int seg = tid + it*256;
      int row = seg >> 3;
      int g   = (5*(seg & 7) + 3*row) & 7;
      gload_lds16(Bt + (n0 + row)*(long)K + k0 + g*16, Bs + seg*16);
    }
    __syncthreads();

    // fragment: lane holds k = q*32..q*32+31 of its row (slots c0, c0+5)
    i32x8 b[FN];
    #pragma unroll
    for (int j = 0; j < FN; ++j) {
      int r = w*64 + j*16 + l16;
      const uint4* p = (const uint4*)(Bs + r*BK);
      int c0 = (2*q + r) & 7;
      union { uint4 v[2]; i32x8 f; } u;
      u.v[0] = p[c0];
      u.v[1] = p[(c0 + 5) & 7];
      b[j] = u.f;
    }
    #pragma unroll
    for (int i = 0; i < FM; ++i) {
      int r = i*16 + l16;
      const uint4* p = (const uint4*)(As + r*BK);
      int c0 = (2*q + r) & 7;
      union { uint4 v[2]; i32x8 f; } u;
      u.v[0] = p[c0];
      u.v[1] = p[(c0 + 5) & 7];
      i32x8 a = u.f;
      #pragma unroll
      for (int j = 0; j < FN; ++j)
        acc[i][j] = __builtin_amdgcn_mfma_scale_f32_16x16x128_f8f6f4(
            a, b[j], acc[i][j], 0, 0, 0, E8M0_ACT, 0, E8M0_W);
    }
    __syncthreads();
  }

  // epilogue: D col = lane&15, row = (lane>>4)*4 + r  [m89/m91 layout]
  if constexpr (ACT == 0) {
    // relu -> fp8 x2^6, repack via smem (row stride 272 = 17x16: aligned,
    // breaks 256-alias). 128 rows x 272 = 34.8KB <= 48KB buffer.
    #pragma unroll
    for (int j = 0; j < FN; ++j) {
      int cl = w*64 + j*16 + l16;
      float bv = bias[n0 + cl];
      #pragma unroll
      for (int i = 0; i < FM; ++i) {
        #pragma unroll
        for (int r = 0; r < 4; ++r) {
          int rl = i*16 + q*4 + r;
          smem[rl*272 + cl] = f2fp8(fmaxf(acc[i][j][r] + bv, 0.f) * ACT_SCALE);
        }
      }
    }
    __syncthreads();
    unsigned char* C = (unsigned char*)Cptr;
    #pragma unroll
    for (int it = 0; it < 8; ++it) {
      int seg = tid + it*256;           // 2048 segs: 128 rows x 16 chunks
      int row = seg >> 4, ch = seg & 15;
      *(uint4*)(C + (m0 + row)*(long)ldC + n0 + ch*16) =
          *(const uint4*)(smem + row*272 + ch*16);
    }
  } else {
    float* C = (float*)Cptr;
    #pragma unroll
    for (int j = 0; j < FN; ++j) {
      long col = n0 + w*64 + j*16 + l16;
      float bv = bias[col];
      #pragma unroll
      for (int i = 0; i < FM; ++i) {
        #pragma unroll
        for (int r = 0; r < 4; ++r) {
          long row = m0 + i*16 + q*4 + r;
          float v = acc[i][j][r] + bv;
          C[row*(long)ldC + col] = 1.f / (1.f + __expf(-v));
        }
      }
    }
  }
}

// ---- fused L2+L3+L4+L5: h1[8 rows] -> d1 (fp8 x2^6), all intermediates in LDS ----
// 8 rows/block, 512 threads (round-8 banked state) + round-10 L4 split
// (t<256: rows 0-3, t>=256: rows 4-7; bit-identical per-row partial tree).
__global__ __launch_bounds__(512) void layer2345(
    const unsigned short* __restrict__ h1,
    const float* __restrict__ W2, const float* __restrict__ C2, const float* __restrict__ b2,
    const float* __restrict__ W3, const float* __restrict__ b3,
    const float* __restrict__ W4, const float* __restrict__ b4,
    const float* __restrict__ Wd1, const float* __restrict__ bd1,
    unsigned char* __restrict__ d1)
{
  __shared__ float h1s[8][200];
  __shared__ float h2s[8][10];
  __shared__ float h3s[8][1024];
  __shared__ float part[8][256];   // [kg][row*32+n]
  __shared__ float zs[8][32];
  const int t = threadIdx.x;               // 0..511
  const int w = t >> 6, l = t & 63;        // wave 0..7
  const long m0 = (long)blockIdx.x * 8;

  for (int e = t; e < 8*196; e += 512) {
    int row = e / 196, col = e - row*196;
    h1s[row][col] = bf2f(h1[(m0 + row)*256 + col]);
  }
  __syncthreads();

  // L2: h2[r][10], wave w handles row w (8 waves, 8 rows)
  {
    float acc[10];
    #pragma unroll
    for (int n = 0; n < 10; ++n) acc[n] = 0.f;
    #pragma unroll
    for (int it = 0; it < 4; ++it) {
      int k = l + it*64;
      if (k < 196) {
        float a = h1s[w][k];
        #pragma unroll
        for (int n = 0; n < 10; ++n) acc[n] += a * W2[k*10 + n] * C2[k*10 + n];
      }
    }
    #pragma unroll
    for (int off = 32; off > 0; off >>= 1) {
      #pragma unroll
      for (int n = 0; n < 10; ++n) acc[n] += __shfl_down(acc[n], off, 64);
    }
    if (l < 10) h2s[w][l] = fmaxf(acc[l] + b2[l], 0.f);
  }
  __syncthreads();

  // L3: h3[r][1024]; wave w covers n = w*128 + jj*64 + l; 8 rows/thread
  #pragma unroll
  for (int jj = 0; jj < 2; ++jj) {
    int n = w*128 + jj*64 + l;
    float a0 = b3[n], a1 = a0, a2 = a0, a3 = a0, a4 = a0, a5 = a0, a6 = a0, a7 = a0;
    #pragma unroll
    for (int k = 0; k < 10; ++k) {
      float wv = W3[k*1024 + n];
      a0 += h2s[0][k]*wv; a1 += h2s[1][k]*wv;
      a2 += h2s[2][k]*wv; a3 += h2s[3][k]*wv;
      a4 += h2s[4][k]*wv; a5 += h2s[5][k]*wv;
      a6 += h2s[6][k]*wv; a7 += h2s[7][k]*wv;
    }
    h3s[0][n] = fmaxf(a0, 0.f); h3s[1][n] = fmaxf(a1, 0.f);
    h3s[2][n] = fmaxf(a2, 0.f); h3s[3][n] = fmaxf(a3, 0.f);
    h3s[4][n] = fmaxf(a4, 0.f); h3s[5][n] = fmaxf(a5, 0.f);
    h3s[6][n] = fmaxf(a6, 0.f); h3s[7][n] = fmaxf(a7, 0.f);
  }
  __syncthreads();

  // L4: all 512 threads: tt = t&255 -> (kg = tt>>5, n = tt&31); t<256 does
  // rows 0-3, t>=256 rows 4-7. Same 8x128 per-row partial tree as before.
  {
    int tt = t & 255;
    int n = tt & 31, kg = tt >> 5;
    int r0 = (t >> 8) * 4;               // 0 or 4
    float a0 = 0.f, a1 = 0.f, a2 = 0.f, a3 = 0.f;
    for (int k = kg*128; k < kg*128 + 128; ++k) {
      float wv = W4[k*32 + n];
      a0 += h3s[r0+0][k]*wv; a1 += h3s[r0+1][k]*wv;
      a2 += h3s[r0+2][k]*wv; a3 += h3s[r0+3][k]*wv;
    }
    part[kg][(r0+0)*32 + n] = a0; part[kg][(r0+1)*32 + n] = a1;
    part[kg][(r0+2)*32 + n] = a2; part[kg][(r0+3)*32 + n] = a3;
  }
  __syncthreads();
  if (t < 256) {
    float s = 0.f;
    #pragma unroll
    for (int kg = 0; kg < 8; ++kg) s += part[kg][t];
    zs[t >> 5][t & 31] = fmaxf(s + b4[t & 31], 0.f);
  }
  __syncthreads();

  // L5: d1[r][1024] fp8 x2^6; wave w covers n = w*128 + jj*64 + l
  #pragma unroll
  for (int jj = 0; jj < 2; ++jj) {
    int n = w*128 + jj*64 + l;
    float a0 = bd1[n], a1 = a0, a2 = a0, a3 = a0, a4 = a0, a5 = a0, a6 = a0, a7 = a0;
    #pragma unroll
    for (int k = 0; k < 32; ++k) {
      float wv = Wd1[k*1024 + n];
      a0 += zs[0][k]*wv; a1 += zs[1][k]*wv;
      a2 += zs[2][k]*wv; a3 += zs[3][k]*wv;
      a4 += zs[4][k]*wv; a5 += zs[5][k]*wv;
      a6 += zs[6][k]*wv; a7 += zs[7][k]*wv;
    }
    d1[(m0 + 0)*1024 + n] = f2fp8(fmaxf(a0, 0.f) * ACT_SCALE);
    d1[(m0 + 1)*1024 + n] = f2fp8(fmaxf(a1, 0.f) * ACT_SCALE);
    d1[(m0 + 2)*1024 + n] = f2fp8(fmaxf(a2, 0.f) * ACT_SCALE);
    d1[(m0 + 3)*1024 + n] = f2fp8(fmaxf(a3, 0.f) * ACT_SCALE);
    d1[(m0 + 4)*1024 + n] = f2fp8(fmaxf(a4, 0.f) * ACT_SCALE);
    d1[(m0 + 5)*1024 + n] = f2fp8(fmaxf(a5, 0.f) * ACT_SCALE);
    d1[(m0 + 6)*1024 + n] = f2fp8(fmaxf(a6, 0.f) * ACT_SCALE);
    d1[(m0 + 7)*1024 + n] = f2fp8(fmaxf(a7, 0.f) * ACT_SCALE);
  }
}

extern "C" void kernel_launch(void* const* d_in, const int* in_sizes, int n_in,
                              void* d_out, int out_size, void* d_ws, size_t ws_size,
                              hipStream_t stream)
{
  (void)in_sizes; (void)n_in; (void)out_size; (void)ws_size;
  const float* x   = (const float*)d_in[0];
  const float* C1  = (const float*)d_in[1];
  const float* W1  = (const float*)d_in[2];
  const float* b1  = (const float*)d_in[3];
  const float* C2  = (const float*)d_in[4];
  const float* W2  = (const float*)d_in[5];
  const float* b2  = (const float*)d_in[6];
  const float* W3  = (const float*)d_in[7];
  const float* b3  = (const float*)d_in[8];
  const float* W4  = (const float*)d_in[9];
  const float* b4  = (const float*)d_in[10];
  const float* Wd1 = (const float*)d_in[11];
  const float* bd1 = (const float*)d_in[12];
  const float* Wd2 = (const float*)d_in[13];
  const float* bd2 = (const float*)d_in[14];
  const float* Wd3 = (const float*)d_in[15];
  const float* bd3 = (const float*)d_in[16];
  float* out = (float*)d_out;

  char* ws = (char*)d_ws;
  size_t off = 0;
  auto alloc = [&](size_t bytes) -> void* {
    void* p = ws + off; off += (bytes + 255) & ~(size_t)255; return p;
  };
  unsigned char* Wt2 = (unsigned char*)alloc((size_t)2048*1024);   // Wd2^T fp8 x16
  unsigned char* Wt3 = (unsigned char*)alloc((size_t)4096*2048);   // Wd3^T fp8 x16
  unsigned*      pk  = (unsigned*)     alloc((size_t)196*21*4);    // packed sparse W1C1
  unsigned short* h1 = (unsigned short*)alloc((size_t)8192*256*2); // bf16
  unsigned char*  d1 = (unsigned char*) alloc((size_t)8192*1024);  // fp8 x2^6
  unsigned char*  d2 = (unsigned char*) alloc((size_t)8192*2048);  // fp8 x2^6

  // prep: one merged launch (build_sparse 196 + Wd2 512 + Wd3 2048 tiles)
  prep_all<<<dim3(196 + 512 + 2048), 256, 0, stream>>>(
      C1, W1, pk, Wd2, Wt2, Wd3, Wt3);

  // L1: h1 = relu(x @ (W1*C1) + b1) — sparse gather, x read once
  layer1_sparse<<<dim3(8192/2), 256, 0, stream>>>(x, pk, b1, h1);
  // L2..L5 fused: 8 rows/block, 512 threads
  layer2345<<<dim3(8192/8), 512, 0, stream>>>(h1, W2, C2, b2, W3, b3, W4, b4,
                                              Wd1, bd1, d1);
  // L6: d2 = relu(d1 @ Wd2 + bd2)  M=8192 N=2048 K=1024  (MX-fp8, 128x256)
  gemm_fp8<0><<<dim3(8192/128, 2048/256), 256, 0, stream>>>(
      d1, Wt2, bd2, d2, 1024, 2048);
  // L7: out = sigmoid(d2 @ Wd3 + bd3)  M=8192 N=4096 K=2048  (MX-fp8, 128x256)
  gemm_fp8<1><<<dim3(8192/128, 4096/256), 256, 0, stream>>>(
      d2, Wt3, bd3, out, 2048, 4096);
}

// Round 12
// 450.398 us; speedup vs baseline: 1.6443x; 1.0009x over previous
//
#include <hip/hip_runtime.h>
#include <hip/hip_fp8.h>
#include <cstdint>
#include <cstddef>

typedef __attribute__((ext_vector_type(4))) float f32x4;
typedef __attribute__((ext_vector_type(8))) int i32x8;

#define DEVINL __device__ __forceinline__

DEVINL unsigned short f2bf(float f){
  union { float f; unsigned u; } v; v.f = f;
  unsigned r = v.u + 0x7fffu + ((v.u >> 16) & 1u);  // RNE
  return (unsigned short)(r >> 16);
}
DEVINL float bf2f(unsigned short h){
  union { unsigned u; float f; } v; v.u = ((unsigned)h) << 16;
  return v.f;
}
DEVINL unsigned char f2fp8(float f){
  __hip_fp8_e4m3 t(f);           // OCP e4m3fn, saturating
  return (unsigned char)t.__x;
}
DEVINL void gload_lds16(const void* g, void* l){
  __builtin_amdgcn_global_load_lds((const __attribute__((address_space(1))) void*)g,
                                   (__attribute__((address_space(3))) void*)l, 16, 0, 0);
}

// scale constants: activations stored x2^6, weights x2^4; descale via e8m0 MFMA scales
#define ACT_SCALE 64.0f
#define W_SCALE   16.0f
#define E8M0_ACT  121   // 2^-6
#define E8M0_W    123   // 2^-4

// ---- merged prep: build_sparse (196 blocks) + both fp8 weight transposes ----
// One launch (R11 banked): build_sparse's latency-bound blocks co-run with
// transpose BW work. Transpose: 64x64 tiles, float4 loads, packed u32 LDS
// writes, uchar4 stores. Same fp8(W[k][n]*16) values to the same Wt[n*K+k]
// addresses -> bit-identical outputs.
// grid: [0,196) build_sparse j=bid; [196,708) Wd2 tiles; [708,2756) Wd3 tiles.
__global__ __launch_bounds__(256) void prep_all(
    const float* __restrict__ C1, const float* __restrict__ W1,
    unsigned* __restrict__ packed,
    const float* __restrict__ Wd2, unsigned char* __restrict__ Wt2,
    const float* __restrict__ Wd3, unsigned char* __restrict__ Wt3)
{
  __shared__ unsigned char tile[64*68];    // 4.25KB (transpose branch)
  __shared__ int wcnt[4], wbase[4];        // (sparse branch)
  const int bid = blockIdx.x;
  const int t = threadIdx.x;

  if (bid < 196) {
    // ---- build_sparse, logic byte-identical to the split kernel ----
    const int j = bid;
    const int w = t >> 6, l = t & 63;
    int cnt = 0;
    #pragma unroll 4
    for (int it = 0; it < 16; ++it) {
      int k = w*1024 + it*64 + l;
      float c = C1[(size_t)k*196 + j];
      unsigned long long m = __ballot(c != 0.f);
      cnt += (int)__popcll(m);
    }
    if (l == 0) wcnt[w] = cnt;
    __syncthreads();
    if (t < 21) packed[j*21 + t] = 0;  // safety vs poison
    if (t == 0) {
      int b = 0;
      #pragma unroll
      for (int i = 0; i < 4; ++i) { wbase[i] = b; b += wcnt[i]; }
    }
    __syncthreads();
    int base = wbase[w];
    #pragma unroll 4
    for (int it = 0; it < 16; ++it) {
      int k = w*1024 + it*64 + l;
      float c = C1[(size_t)k*196 + j];
      unsigned long long m = __ballot(c != 0.f);
      if (c != 0.f) {
        int pos = base + (int)__popcll(m & ((1ull << l) - 1ull));
        if (pos < 21)
          packed[j*21 + pos] = ((unsigned)k << 16)
                             | (unsigned)f2bf(W1[(size_t)k*196 + j] * c);
      }
      base += (int)__popcll(m);
    }
  } else {
    // ---- fp8 transpose, 64x64 tile ----
    const float* W; unsigned char* Wt; int K, N, tid;
    if (bid < 196 + 512) { W = Wd2; Wt = Wt2; K = 1024; N = 2048; tid = bid - 196; }
    else                 { W = Wd3; Wt = Wt3; K = 2048; N = 4096; tid = bid - 708; }
    const int ktiles = K >> 6;
    const int k0 = (tid % ktiles) * 64, n0 = (tid / ktiles) * 64;
    const int lr = t >> 4, lc4 = (t & 15) * 4;
    // load 4 rows-of-16-threads x float4, convert, packed u32 LDS write
    #pragma unroll
    for (int it = 0; it < 4; ++it) {
      int kl = lr + it*16;
      float4 v = *(const float4*)(W + (size_t)(k0 + kl)*N + n0 + lc4);
      unsigned u = (unsigned)f2fp8(v.x * W_SCALE)
                 | ((unsigned)f2fp8(v.y * W_SCALE) << 8)
                 | ((unsigned)f2fp8(v.z * W_SCALE) << 16)
                 | ((unsigned)f2fp8(v.w * W_SCALE) << 24);
      *(unsigned*)(tile + kl*68 + lc4) = u;
    }
    __syncthreads();
    // store: thread covers 4 consecutive k for its n -> uchar4 (u32) store
    #pragma unroll
    for (int it = 0; it < 4; ++it) {
      int nl = lr + it*16;
      unsigned u = (unsigned)tile[(lc4+0)*68 + nl]
                 | ((unsigned)tile[(lc4+1)*68 + nl] << 8)
                 | ((unsigned)tile[(lc4+2)*68 + nl] << 16)
                 | ((unsigned)tile[(lc4+3)*68 + nl] << 24);
      *(unsigned*)(Wt + (size_t)(n0 + nl)*K + k0 + lc4) = u;
    }
  }
}

// ---- L1: h1 = relu(x @ sparse(W1*C1) + b1), 2 rows/block, x read exactly once ----
// Round-12 change (one variable): 512 threads instead of 256. 32KB LDS ->
// 4 blocks/CU (wave cap) x 8 waves = 32 waves/CU (was 20) -> +60% staging
// in flight toward the 128MB HBM-read floor; gather collapses to one t<392
// pass (was 2 passes with half-idle second pass). Same per-output sum order
// -> bit-identical h1.
__global__ __launch_bounds__(512) void layer1_sparse(
    const float* __restrict__ x, const unsigned* __restrict__ packed,
    const float* __restrict__ b1, unsigned short* __restrict__ h1)
{
  __shared__ __align__(16) float xs[2*4096];
  const int t = threadIdx.x;
  const long m0 = (long)blockIdx.x * 2;
  const char* src = (const char*)(x + m0*4096);
  #pragma unroll
  for (int i = 0; i < 4; ++i) {
    int seg = t + i*512;                       // 0..2047, 16B each
    gload_lds16(src + (size_t)seg*16, (char*)xs + (size_t)seg*16);
  }
  __syncthreads();
  if (t < 2*196) {
    int row = (t >= 196) ? 1 : 0;
    int col = t - row*196;
    const float* xr = xs + row*4096;
    float acc = b1[col];
    #pragma unroll
    for (int i = 0; i < 21; ++i) {
      unsigned p = packed[col*21 + i];          // L1-hot 16.5 KB table
      acc += xr[p >> 16] * bf2f((unsigned short)(p & 0xffffu));
    }
    h1[(m0 + row)*256 + col] = f2bf(fmaxf(acc, 0.f));
  }
}

// ---- MX-fp8 MFMA GEMM: C = act(A[M,K] * Bt[N,K]^T + bias) ----
// EXACT round-8 banked structure (measured best: ~84us, MfmaUtil 33%):
// 128x256 block tile, per-wave 128x64 (FM=8, FN=4, 4 waves as n-slots),
// single-buffered 48KB static LDS, (5g+r)&7 chunk swizzle, full-line
// gload_lds staging. ~240 regs/wave -> 2 blocks/CU; cross-block wave
// overlap (m114) hides the barrier drain. Measured-closed alternatives:
// R1/R7 dbuf schedules (drain kills prefetch; 1 blk/CU lockstep),
// R2 conflict-free read layout (half-line staging), R9 FN=8 (acc=256
// VGPR -> scratch spill, 637MB fetch), XCD swizzle (analytic: default
// mapping already A-localized; kernel stall-bound at 28% HBM anyway).
// ACT 0: relu -> fp8 x2^6 (LDS repack, stride 272, coalesced 16B stores);
// ACT 1: sigmoid -> fp32. Grid (M/128, N/256), 256 threads.
template<int ACT>
__global__ __launch_bounds__(256, 2) void gemm_fp8(
    const unsigned char* __restrict__ A, const unsigned char* __restrict__ Bt,
    const float* __restrict__ bias, void* __restrict__ Cptr, int K, int ldC)
{
  constexpr int BM = 128, BN = 256, BK = 128;
  constexpr int FM = 8, FN = 4;
  __shared__ __align__(16) unsigned char smem[49152];
  unsigned char* As = smem;             // 16KB: 128 rows x 128B
  unsigned char* Bs = smem + 16384;     // 32KB: 256 rows x 128B
  const int tid  = threadIdx.x;
  const int lane = tid & 63;
  const int w    = tid >> 6;            // wave n-slot 0..3
  const int q = lane >> 4, l16 = lane & 15;
  const long m0 = (long)blockIdx.x * BM;
  const long n0 = (long)blockIdx.y * BN;

  f32x4 acc[FM][FN] = {};

  for (int k0 = 0; k0 < K; k0 += BK) {
    #pragma unroll
    for (int it = 0; it < 4; ++it) {
      int seg = tid + it*256;
      int row = seg >> 3;
      int g   = (5*(seg & 7) + 3*row) & 7;
      gload_lds16(A + (m0 + row)*(long)K + k0 + g*16, As + seg*16);
    }
    #pragma unroll
    for (int it = 0; it < 8; ++it) {
      int seg = tid + it*256;
      int row = seg >> 3;
      int g   = (5*(seg & 7) + 3*row) & 7;
      gload_lds16(Bt + (n0 + row)*(long)K + k0 + g*16, Bs + seg*16);
    }
    __syncthreads();

    // fragment: lane holds k = q*32..q*32+31 of its row (slots c0, c0+5)
    i32x8 b[FN];
    #pragma unroll
    for (int j = 0; j < FN; ++j) {
      int r = w*64 + j*16 + l16;
      const uint4* p = (const uint4*)(Bs + r*BK);
      int c0 = (2*q + r) & 7;
      union { uint4 v[2]; i32x8 f; } u;
      u.v[0] = p[c0];
      u.v[1] = p[(c0 + 5) & 7];
      b[j] = u.f;
    }
    #pragma unroll
    for (int i = 0; i < FM; ++i) {
      int r = i*16 + l16;
      const uint4* p = (const uint4*)(As + r*BK);
      int c0 = (2*q + r) & 7;
      union { uint4 v[2]; i32x8 f; } u;
      u.v[0] = p[c0];
      u.v[1] = p[(c0 + 5) & 7];
      i32x8 a = u.f;
      #pragma unroll
      for (int j = 0; j < FN; ++j)
        acc[i][j] = __builtin_amdgcn_mfma_scale_f32_16x16x128_f8f6f4(
            a, b[j], acc[i][j], 0, 0, 0, E8M0_ACT, 0, E8M0_W);
    }
    __syncthreads();
  }

  // epilogue: D col = lane&15, row = (lane>>4)*4 + r  [m89/m91 layout]
  if constexpr (ACT == 0) {
    // relu -> fp8 x2^6, repack via smem (row stride 272 = 17x16: aligned,
    // breaks 256-alias). 128 rows x 272 = 34.8KB <= 48KB buffer.
    #pragma unroll
    for (int j = 0; j < FN; ++j) {
      int cl = w*64 + j*16 + l16;
      float bv = bias[n0 + cl];
      #pragma unroll
      for (int i = 0; i < FM; ++i) {
        #pragma unroll
        for (int r = 0; r < 4; ++r) {
          int rl = i*16 + q*4 + r;
          smem[rl*272 + cl] = f2fp8(fmaxf(acc[i][j][r] + bv, 0.f) * ACT_SCALE);
        }
      }
    }
    __syncthreads();
    unsigned char* C = (unsigned char*)Cptr;
    #pragma unroll
    for (int it = 0; it < 8; ++it) {
      int seg = tid + it*256;           // 2048 segs: 128 rows x 16 chunks
      int row = seg >> 4, ch = seg & 15;
      *(uint4*)(C + (m0 + row)*(long)ldC + n0 + ch*16) =
          *(const uint4*)(smem + row*272 + ch*16);
    }
  } else {
    float* C = (float*)Cptr;
    #pragma unroll
    for (int j = 0; j < FN; ++j) {
      long col = n0 + w*64 + j*16 + l16;
      float bv = bias[col];
      #pragma unroll
      for (int i = 0; i < FM; ++i) {
        #pragma unroll
        for (int r = 0; r < 4; ++r) {
          long row = m0 + i*16 + q*4 + r;
          float v = acc[i][j][r] + bv;
          C[row*(long)ldC + col] = 1.f / (1.f + __expf(-v));
        }
      }
    }
  }
}

// ---- fused L2+L3+L4+L5: h1[8 rows] -> d1 (fp8 x2^6), all intermediates in LDS ----
// 8 rows/block, 512 threads (round-8 banked state) + round-10 L4 split
// (t<256: rows 0-3, t>=256: rows 4-7; bit-identical per-row partial tree).
__global__ __launch_bounds__(512) void layer2345(
    const unsigned short* __restrict__ h1,
    const float* __restrict__ W2, const float* __restrict__ C2, const float* __restrict__ b2,
    const float* __restrict__ W3, const float* __restrict__ b3,
    const float* __restrict__ W4, const float* __restrict__ b4,
    const float* __restrict__ Wd1, const float* __restrict__ bd1,
    unsigned char* __restrict__ d1)
{
  __shared__ float h1s[8][200];
  __shared__ float h2s[8][10];
  __shared__ float h3s[8][1024];
  __shared__ float part[8][256];   // [kg][row*32+n]
  __shared__ float zs[8][32];
  const int t = threadIdx.x;               // 0..511
  const int w = t >> 6, l = t & 63;        // wave 0..7
  const long m0 = (long)blockIdx.x * 8;

  for (int e = t; e < 8*196; e += 512) {
    int row = e / 196, col = e - row*196;
    h1s[row][col] = bf2f(h1[(m0 + row)*256 + col]);
  }
  __syncthreads();

  // L2: h2[r][10], wave w handles row w (8 waves, 8 rows)
  {
    float acc[10];
    #pragma unroll
    for (int n = 0; n < 10; ++n) acc[n] = 0.f;
    #pragma unroll
    for (int it = 0; it < 4; ++it) {
      int k = l + it*64;
      if (k < 196) {
        float a = h1s[w][k];
        #pragma unroll
        for (int n = 0; n < 10; ++n) acc[n] += a * W2[k*10 + n] * C2[k*10 + n];
      }
    }
    #pragma unroll
    for (int off = 32; off > 0; off >>= 1) {
      #pragma unroll
      for (int n = 0; n < 10; ++n) acc[n] += __shfl_down(acc[n], off, 64);
    }
    if (l < 10) h2s[w][l] = fmaxf(acc[l] + b2[l], 0.f);
  }
  __syncthreads();

  // L3: h3[r][1024]; wave w covers n = w*128 + jj*64 + l; 8 rows/thread
  #pragma unroll
  for (int jj = 0; jj < 2; ++jj) {
    int n = w*128 + jj*64 + l;
    float a0 = b3[n], a1 = a0, a2 = a0, a3 = a0, a4 = a0, a5 = a0, a6 = a0, a7 = a0;
    #pragma unroll
    for (int k = 0; k < 10; ++k) {
      float wv = W3[k*1024 + n];
      a0 += h2s[0][k]*wv; a1 += h2s[1][k]*wv;
      a2 += h2s[2][k]*wv; a3 += h2s[3][k]*wv;
      a4 += h2s[4][k]*wv; a5 += h2s[5][k]*wv;
      a6 += h2s[6][k]*wv; a7 += h2s[7][k]*wv;
    }
    h3s[0][n] = fmaxf(a0, 0.f); h3s[1][n] = fmaxf(a1, 0.f);
    h3s[2][n] = fmaxf(a2, 0.f); h3s[3][n] = fmaxf(a3, 0.f);
    h3s[4][n] = fmaxf(a4, 0.f); h3s[5][n] = fmaxf(a5, 0.f);
    h3s[6][n] = fmaxf(a6, 0.f); h3s[7][n] = fmaxf(a7, 0.f);
  }
  __syncthreads();

  // L4: all 512 threads: tt = t&255 -> (kg = tt>>5, n = tt&31); t<256 does
  // rows 0-3, t>=256 rows 4-7. Same 8x128 per-row partial tree as before.
  {
    int tt = t & 255;
    int n = tt & 31, kg = tt >> 5;
    int r0 = (t >> 8) * 4;               // 0 or 4
    float a0 = 0.f, a1 = 0.f, a2 = 0.f, a3 = 0.f;
    for (int k = kg*128; k < kg*128 + 128; ++k) {
      float wv = W4[k*32 + n];
      a0 += h3s[r0+0][k]*wv; a1 += h3s[r0+1][k]*wv;
      a2 += h3s[r0+2][k]*wv; a3 += h3s[r0+3][k]*wv;
    }
    part[kg][(r0+0)*32 + n] = a0; part[kg][(r0+1)*32 + n] = a1;
    part[kg][(r0+2)*32 + n] = a2; part[kg][(r0+3)*32 + n] = a3;
  }
  __syncthreads();
  if (t < 256) {
    float s = 0.f;
    #pragma unroll
    for (int kg = 0; kg < 8; ++kg) s += part[kg][t];
    zs[t >> 5][t & 31] = fmaxf(s + b4[t & 31], 0.f);
  }
  __syncthreads();

  // L5: d1[r][1024] fp8 x2^6; wave w covers n = w*128 + jj*64 + l
  #pragma unroll
  for (int jj = 0; jj < 2; ++jj) {
    int n = w*128 + jj*64 + l;
    float a0 = bd1[n], a1 = a0, a2 = a0, a3 = a0, a4 = a0, a5 = a0, a6 = a0, a7 = a0;
    #pragma unroll
    for (int k = 0; k < 32; ++k) {
      float wv = Wd1[k*1024 + n];
      a0 += zs[0][k]*wv; a1 += zs[1][k]*wv;
      a2 += zs[2][k]*wv; a3 += zs[3][k]*wv;
      a4 += zs[4][k]*wv; a5 += zs[5][k]*wv;
      a6 += zs[6][k]*wv; a7 += zs[7][k]*wv;
    }
    d1[(m0 + 0)*1024 + n] = f2fp8(fmaxf(a0, 0.f) * ACT_SCALE);
    d1[(m0 + 1)*1024 + n] = f2fp8(fmaxf(a1, 0.f) * ACT_SCALE);
    d1[(m0 + 2)*1024 + n] = f2fp8(fmaxf(a2, 0.f) * ACT_SCALE);
    d1[(m0 + 3)*1024 + n] = f2fp8(fmaxf(a3, 0.f) * ACT_SCALE);
    d1[(m0 + 4)*1024 + n] = f2fp8(fmaxf(a4, 0.f) * ACT_SCALE);
    d1[(m0 + 5)*1024 + n] = f2fp8(fmaxf(a5, 0.f) * ACT_SCALE);
    d1[(m0 + 6)*1024 + n] = f2fp8(fmaxf(a6, 0.f) * ACT_SCALE);
    d1[(m0 + 7)*1024 + n] = f2fp8(fmaxf(a7, 0.f) * ACT_SCALE);
  }
}

extern "C" void kernel_launch(void* const* d_in, const int* in_sizes, int n_in,
                              void* d_out, int out_size, void* d_ws, size_t ws_size,
                              hipStream_t stream)
{
  (void)in_sizes; (void)n_in; (void)out_size; (void)ws_size;
  const float* x   = (const float*)d_in[0];
  const float* C1  = (const float*)d_in[1];
  const float* W1  = (const float*)d_in[2];
  const float* b1  = (const float*)d_in[3];
  const float* C2  = (const float*)d_in[4];
  const float* W2  = (const float*)d_in[5];
  const float* b2  = (const float*)d_in[6];
  const float* W3  = (const float*)d_in[7];
  const float* b3  = (const float*)d_in[8];
  const float* W4  = (const float*)d_in[9];
  const float* b4  = (const float*)d_in[10];
  const float* Wd1 = (const float*)d_in[11];
  const float* bd1 = (const float*)d_in[12];
  const float* Wd2 = (const float*)d_in[13];
  const float* bd2 = (const float*)d_in[14];
  const float* Wd3 = (const float*)d_in[15];
  const float* bd3 = (const float*)d_in[16];
  float* out = (float*)d_out;

  char* ws = (char*)d_ws;
  size_t off = 0;
  auto alloc = [&](size_t bytes) -> void* {
    void* p = ws + off; off += (bytes + 255) & ~(size_t)255; return p;
  };
  unsigned char* Wt2 = (unsigned char*)alloc((size_t)2048*1024);   // Wd2^T fp8 x16
  unsigned char* Wt3 = (unsigned char*)alloc((size_t)4096*2048);   // Wd3^T fp8 x16
  unsigned*      pk  = (unsigned*)     alloc((size_t)196*21*4);    // packed sparse W1C1
  unsigned short* h1 = (unsigned short*)alloc((size_t)8192*256*2); // bf16
  unsigned char*  d1 = (unsigned char*) alloc((size_t)8192*1024);  // fp8 x2^6
  unsigned char*  d2 = (unsigned char*) alloc((size_t)8192*2048);  // fp8 x2^6

  // prep: one merged launch (build_sparse 196 + Wd2 512 + Wd3 2048 tiles)
  prep_all<<<dim3(196 + 512 + 2048), 256, 0, stream>>>(
      C1, W1, pk, Wd2, Wt2, Wd3, Wt3);

  // L1: h1 = relu(x @ (W1*C1) + b1) — sparse gather, x read once, 512 threads
  layer1_sparse<<<dim3(8192/2), 512, 0, stream>>>(x, pk, b1, h1);
  // L2..L5 fused: 8 rows/block, 512 threads
  layer2345<<<dim3(8192/8), 512, 0, stream>>>(h1, W2, C2, b2, W3, b3, W4, b4,
                                              Wd1, bd1, d1);
  // L6: d2 = relu(d1 @ Wd2 + bd2)  M=8192 N=2048 K=1024  (MX-fp8, 128x256)
  gemm_fp8<0><<<dim3(8192/128, 2048/256), 256, 0, stream>>>(
      d1, Wt2, bd2, d2, 1024, 2048);
  // L7: out = sigmoid(d2 @ Wd3 + bd3)  M=8192 N=4096 K=2048  (MX-fp8, 128x256)
  gemm_fp8<1><<<dim3(8192/128, 4096/256), 256, 0, stream>>>(
      d2, Wt3, bd3, out, 2048, 4096);
}